// Round 7
// baseline (456.080 us; speedup 1.0000x reference)
//
#include <hip/hip_runtime.h>

#define NN 64
#define CI 128
#define HD 128
#define KC 5
#define AJW 17    // byte-packed adj row stride in words (16 used + 1 pad)

// ws layout (floats): [0,768) Wc[128][6] = [Wp | y] row-major; ws[768]=b1.z ; ws[769]=b2.Wl
#define WS_WC  0
#define WS_B1Z 768
#define WS_B2W 769

// ---------------- pre-kernel: weights-only folding (1 block, 64 threads) ----------------
extern "C" __global__ void zprep(const float* __restrict__ W1,
                                 const float* __restrict__ Wp,
                                 const float* __restrict__ W2,
                                 const float* __restrict__ Wl,
                                 const float* __restrict__ b1,
                                 const float* __restrict__ b2,
                                 float* __restrict__ ws)
{
    const int t = threadIdx.x;
    __shared__ float sz_[HD];
    // z = W2 @ Wl
    float a0 = 0.f, a1 = 0.f;
    for (int c = 0; c < HD; ++c) {
        const float wl = Wl[c];
        a0 += W2[t * HD + c] * wl;
        a1 += W2[(t + 64) * HD + c] * wl;
    }
    sz_[t] = a0; sz_[t + 64] = a1;
    float p1 = b1[t] * a0 + b1[t + 64] * a1;
    float p2 = b2[t] * Wl[t] + b2[t + 64] * Wl[t + 64];
    #pragma unroll
    for (int off = 32; off; off >>= 1) {
        p1 += __shfl_down(p1, off, 64);
        p2 += __shfl_down(p2, off, 64);
    }
    if (t == 0) { ws[WS_B1Z] = p1; ws[WS_B2W] = p2; }
    __syncthreads();
    // y = W1 @ z ; Wc[c][0..4] = Wp[c][*], Wc[c][5] = y[c]
    #pragma unroll
    for (int rr = 0; rr < 2; ++rr) {
        const int r = t + rr * 64;
        float acc = 0.f;
        for (int h2 = 0; h2 < HD; ++h2) acc += W1[r * HD + h2] * sz_[h2];
        #pragma unroll
        for (int k = 0; k < KC; ++k) ws[WS_WC + r * 6 + k] = Wp[r * KC + k];
        ws[WS_WC + r * 6 + 5] = acc;
    }
}

#define EDGE(sv_, dv_) { const int s_ = (sv_) & 63, d_ = (dv_) & 63; \
    atomicAdd(&adj[s_][d_ >> 2], 1u << ((d_ & 3) * 8)); }

// ---------------- main kernel: ONE GRAPH PER WAVE, zero barriers ----------------
extern "C" __global__ __launch_bounds__(256, 6)
void diffpool_main(const float* __restrict__ x,
                   const int* __restrict__ ei,
                   const float* __restrict__ bp,
                   const float* __restrict__ bl,
                   const float* __restrict__ ws,
                   float* __restrict__ out,
                   int E, int epg, int B)
{
    __shared__ __attribute__((aligned(16))) unsigned int sadjb[4][NN][AJW]; // 17408 B
    __shared__ __attribute__((aligned(16))) float sSm[4][NN][8];            // 8192 B
    // row layout: [s0,s1,s2,s3 | s4, q, d, pad]

    const int t = threadIdx.x;
    const int lane = t & 63;
    const int wv = t >> 6;
    const int g = blockIdx.x * 4 + wv;    // one graph per wave
    if (g >= B) return;                   // safe: no barriers anywhere in this kernel

    unsigned int (*adj)[AJW] = sadjb[wv];
    float (*sm)[8] = sSm[wv];

    const int n = lane;
    const int ch = lane & 15;     // column chunk (16 lanes per row)
    const int rg = lane >> 4;     // row group 0..3

    // uniform scalars (SGPR)
    const float bp0 = bp[0], bp1 = bp[1], bp2 = bp[2], bp3 = bp[3], bp4 = bp[4];
    const float c_b1z = ws[WS_B1Z], c_b2w = ws[WS_B2W], c_bl = bl[0];

    // ---- edge loads first (latency hides under zero/x phases) ----
    const int base = g * epg;
    int4 es0, es1, ed0, ed1;
    const bool fast = (epg == 512);
    if (fast) {
        es0 = *reinterpret_cast<const int4*>(ei + base + lane * 8);
        es1 = *reinterpret_cast<const int4*>(ei + base + lane * 8 + 4);
        ed0 = *reinterpret_cast<const int4*>(ei + E + base + lane * 8);
        ed1 = *reinterpret_cast<const int4*>(ei + E + base + lane * 8 + 4);
    }

    // ---- zero own adjacency row (wave-internal; precedes atomics in program order) ----
    #pragma unroll
    for (int i = 0; i < AJW; ++i) adj[lane][i] = 0u;

    // ---- adjacency atomics (byte-packed, wave-private region) ----
    if (fast) {
        EDGE(es0.x, ed0.x); EDGE(es0.y, ed0.y); EDGE(es0.z, ed0.z); EDGE(es0.w, ed0.w);
        EDGE(es1.x, ed1.x); EDGE(es1.y, ed1.y); EDGE(es1.z, ed1.z); EDGE(es1.w, ed1.w);
    } else {
        for (int j = lane; j < epg; j += 64) {
            const int sn = ei[base + j] & 63;
            const int dn = ei[E + base + j] & 63;
            atomicAdd(&adj[sn][dn >> 2], 1u << ((dn & 3) * 8));
        }
    }

    // ---- P1: coalesced x loads fused into S0 = x@Wp and q = x.y (f32 exact) ----
    {
        float wc[48];   // Wc rows ch*8..+8, 6 cols (L2-hot)
        const float4* wc4 = reinterpret_cast<const float4*>(ws + WS_WC + ch * 48);
        #pragma unroll
        for (int i4 = 0; i4 < 12; ++i4)
            *reinterpret_cast<float4*>(&wc[i4 * 4]) = wc4[i4];
        const float* xg = x + (size_t)g * (NN * CI);
        #pragma unroll 4
        for (int i = 0; i < 16; ++i) {
            const int row = rg + 4 * i;           // wave covers 4 consecutive rows = 2KB dense
            const float* xr = xg + row * CI + ch * 8;
            const float4 v0 = *reinterpret_cast<const float4*>(xr);
            const float4 v1 = *reinterpret_cast<const float4*>(xr + 4);
            float acc[6];
            #pragma unroll
            for (int k = 0; k < 6; ++k)
                acc[k] = v0.x * wc[0*6+k] + v0.y * wc[1*6+k] + v0.z * wc[2*6+k] + v0.w * wc[3*6+k]
                       + v1.x * wc[4*6+k] + v1.y * wc[5*6+k] + v1.z * wc[6*6+k] + v1.w * wc[7*6+k];
            #pragma unroll
            for (int k = 0; k < 6; ++k) {
                float r = acc[k];
                r += __shfl_xor(r, 1, 16);
                r += __shfl_xor(r, 2, 16);
                r += __shfl_xor(r, 4, 16);
                r += __shfl_xor(r, 8, 16);
                acc[k] = r;
            }
            float val = acc[0];
            #pragma unroll
            for (int k = 1; k < 6; ++k) val = (ch == k) ? acc[k] : val;
            if (ch < 6)      sm[row][ch] = val;   // banks rg*8+ch: conflict-free
            else if (ch < 8) sm[row][ch] = 0.f;   // init d/pad slots (d overwritten in S1)
        }
    }

    // ---- S1: adjacency row -> regs; degree from byte sums; d; s_pre + c (full, in regs) ----
    unsigned w[16];
    #pragma unroll
    for (int i = 0; i < 16; ++i) w[i] = adj[n][i];   // 2-way max bank alias: free
    unsigned acc1 = 0u, acc2 = 0u;
    #pragma unroll
    for (int i = 0; i < 16; ++i) {
        acc1 += w[i] & 0x00FF00FFu;
        acc2 += (w[i] >> 8) & 0x00FF00FFu;
    }
    const unsigned rowsum = (acc1 & 0xFFFFu) + (acc1 >> 16) + (acc2 & 0xFFFFu) + (acc2 >> 16);
    const unsigned selfb = (adj[n][n >> 2] >> ((n & 3) * 8)) & 255u;  // single LDS read
    const float dlane = rsqrtf((float)(rowsum + 1u - selfb));
    sm[n][6] = dlane;    // same-wave write; later broadcast reads are program-ordered

    float a0 = 0.f, a1 = 0.f, a2 = 0.f, a3 = 0.f, a4 = 0.f, cp = 0.f;
    #pragma unroll
    for (int i = 0; i < 16; ++i) {
        #pragma unroll
        for (int b = 0; b < 4; ++b) {
            const int m = i * 4 + b;
            float al = (float)((w[i] >> (b * 8)) & 255u);
            al = (m == n) ? 1.f : al;
            const float4 s01 = *reinterpret_cast<const float4*>(&sm[m][0]); // broadcast
            const float4 s23 = *reinterpret_cast<const float4*>(&sm[m][4]); // {s4,q,d,pad}
            const float f = al * s23.z;             // al * d[m]
            a0 += f * s01.x; a1 += f * s01.y; a2 += f * s01.z; a3 += f * s01.w;
            a4 += f * s23.x;
            cp += f * s23.y;                        // c[n] += adj_l*d[m]*q[m]
        }
    }

    // ---- S2: softmax in registers; publish s to own row ----
    a0 = a0 * dlane + bp0; a1 = a1 * dlane + bp1; a2 = a2 * dlane + bp2;
    a3 = a3 * dlane + bp3; a4 = a4 * dlane + bp4;
    const float mx = fmaxf(fmaxf(fmaxf(a0, a1), fmaxf(a2, a3)), a4);
    a0 = expf(a0 - mx); a1 = expf(a1 - mx); a2 = expf(a2 - mx);
    a3 = expf(a3 - mx); a4 = expf(a4 - mx);
    const float inv = 1.f / (a0 + a1 + a2 + a3 + a4);
    float sv[5];
    sv[0] = a0 * inv; sv[1] = a1 * inv; sv[2] = a2 * inv; sv[3] = a3 * inv; sv[4] = a4 * inv;
    {   // overwrite S0 with softmaxed s (S1 reads already issued — wave program order)
        float4 s01; s01.x = sv[0]; s01.y = sv[1]; s01.z = sv[2]; s01.w = sv[3];
        *reinterpret_cast<float4*>(&sm[n][0]) = s01;
        sm[n][4] = sv[4];
    }

    // ---- S3: U[n][:] = sum_m adj[n][m] * s[m][:] (raw adj), in registers ----
    float uv[5] = {0.f, 0.f, 0.f, 0.f, 0.f};
    #pragma unroll
    for (int i = 0; i < 16; ++i) {
        #pragma unroll
        for (int b = 0; b < 4; ++b) {
            const int m = i * 4 + b;
            const float c = (float)((w[i] >> (b * 8)) & 255u);
            const float4 s03 = *reinterpret_cast<const float4*>(&sm[m][0]); // broadcast
            const float s4r = sm[m][4];
            uv[0] += c * s03.x; uv[1] += c * s03.y; uv[2] += c * s03.z;
            uv[3] += c * s03.w; uv[4] += c * s4r;
        }
    }

    // ---- S4: adjp = s^T U via lane-outer-product + 25-value wave butterfly ----
    float pr[25];
    #pragma unroll
    for (int k = 0; k < 5; ++k)
        #pragma unroll
        for (int l = 0; l < 5; ++l)
            pr[k * 5 + l] = sv[k] * uv[l];
    #pragma unroll
    for (int p = 0; p < 25; ++p) {
        float r = pr[p];
        r += __shfl_xor(r, 1, 64);
        r += __shfl_xor(r, 2, 64);
        r += __shfl_xor(r, 4, 64);
        r += __shfl_xor(r, 8, 64);
        r += __shfl_xor(r, 16, 64);
        r += __shfl_xor(r, 32, 64);
        pr[p] = r;      // all lanes now hold full adjp
    }

    // ---- S5: per-lane redundant scalar chain -> w[n], then final reduce ----
    float d2[5], cf[5];
    #pragma unroll
    for (int k = 0; k < 5; ++k) {
        float s_ = pr[k*5+0] + pr[k*5+1] + pr[k*5+2] + pr[k*5+3] + pr[k*5+4];
        s_ += 1.f - pr[k * 6];
        d2[k] = rsqrtf(fmaxf(s_, 1.f));
    }
    #pragma unroll
    for (int l = 0; l < 5; ++l) {
        float a = 0.f;
        #pragma unroll
        for (int k = 0; k < 5; ++k) a += d2[k] * pr[k * 5 + l];
        a += d2[l] * (1.f - pr[l * 6]);
        cf[l] = d2[l] * a;
    }
    const float t5 = cf[0]*sv[0] + cf[1]*sv[1] + cf[2]*sv[2] + cf[3]*sv[3] + cf[4]*sv[4];
    float v  = (dlane * t5) * cp;   // w[n] * c[n]
    float cb = t5;
    #pragma unroll
    for (int off = 32; off; off >>= 1) {
        v  += __shfl_down(v,  off, 64);
        cb += __shfl_down(cb, off, 64);
    }
    if (lane == 0)
        out[g] = v + cb * c_b1z + 5.f * c_b2w + c_bl;
}

extern "C" void kernel_launch(void* const* d_in, const int* in_sizes, int n_in,
                              void* d_out, int out_size, void* d_ws, size_t ws_size,
                              hipStream_t stream) {
    const float* x  = (const float*)d_in[0];
    const int*   ei = (const int*)d_in[1];
    // d_in[2] = batch (layout implied; unused)
    const float* Wp = (const float*)d_in[3];
    const float* bp = (const float*)d_in[4];
    const float* W1 = (const float*)d_in[5];
    const float* b1 = (const float*)d_in[6];
    const float* W2 = (const float*)d_in[7];
    const float* b2 = (const float*)d_in[8];
    const float* Wl = (const float*)d_in[9];
    const float* bl = (const float*)d_in[10];
    float* out = (float*)d_out;
    float* ws  = (float*)d_ws;

    const int B = out_size;            // 8192 graphs
    const int E = in_sizes[1] / 2;     // edge_index is [2, E]
    const int epg = E / B;             // 512 edges per graph

    zprep<<<1, 64, 0, stream>>>(W1, Wp, W2, Wl, b1, b2, ws);
    const int nb = (B + 3) / 4;        // 4 graphs (waves) per block
    diffpool_main<<<nb, 256, 0, stream>>>(x, ei, bp, bl, ws, out, E, epg, B);
}

// Round 8
// 438.569 us; speedup vs baseline: 1.0399x; 1.0399x over previous
//
#include <hip/hip_runtime.h>

#define NN 64
#define CI 128
#define HD 128
#define KC 5
#define AJW 17    // byte-packed adj row stride in words (16 used + 1 pad)

// ws layout (floats): [0,768) Wc[128][6] = [Wp | y] row-major; ws[768]=b1.z ; ws[769]=b2.Wl
#define WS_WC  0
#define WS_B1Z 768
#define WS_B2W 769

typedef unsigned int u32;
typedef __attribute__((address_space(1))) const u32* gas_p;
typedef __attribute__((address_space(3))) u32* las_p;

__device__ __forceinline__ void gload_lds16(const void* g, void* l) {
    // DMA 16B/lane global->LDS; LDS dest = uniform base + lane*16 (HW); global src per-lane
    __builtin_amdgcn_global_load_lds((gas_p)g, (las_p)l, 16, 0, 0);
}

// ---------------- pre-kernel: weights-only folding (1 block, 64 threads) ----------------
extern "C" __global__ void zprep(const float* __restrict__ W1,
                                 const float* __restrict__ Wp,
                                 const float* __restrict__ W2,
                                 const float* __restrict__ Wl,
                                 const float* __restrict__ b1,
                                 const float* __restrict__ b2,
                                 float* __restrict__ ws)
{
    const int t = threadIdx.x;
    __shared__ float sz_[HD];
    // z = W2 @ Wl
    float a0 = 0.f, a1 = 0.f;
    for (int c = 0; c < HD; ++c) {
        const float wl = Wl[c];
        a0 += W2[t * HD + c] * wl;
        a1 += W2[(t + 64) * HD + c] * wl;
    }
    sz_[t] = a0; sz_[t + 64] = a1;
    float p1 = b1[t] * a0 + b1[t + 64] * a1;
    float p2 = b2[t] * Wl[t] + b2[t + 64] * Wl[t + 64];
    #pragma unroll
    for (int off = 32; off; off >>= 1) {
        p1 += __shfl_down(p1, off, 64);
        p2 += __shfl_down(p2, off, 64);
    }
    if (t == 0) { ws[WS_B1Z] = p1; ws[WS_B2W] = p2; }
    __syncthreads();
    // y = W1 @ z ; Wc[c][0..4] = Wp[c][*], Wc[c][5] = y[c]
    #pragma unroll
    for (int rr = 0; rr < 2; ++rr) {
        const int r = t + rr * 64;
        float acc = 0.f;
        for (int h2 = 0; h2 < HD; ++h2) acc += W1[r * HD + h2] * sz_[h2];
        #pragma unroll
        for (int k = 0; k < KC; ++k) ws[WS_WC + r * 6 + k] = Wp[r * KC + k];
        ws[WS_WC + r * 6 + 5] = acc;
    }
}

#define EDGE(sv_, dv_) { const int s_ = (sv_) & 63, d_ = (dv_) & 63; \
    atomicAdd(&adj[s_][d_ >> 2], 1u << ((d_ & 3) * 8)); }

// ---------------- main kernel: ONE GRAPH PER WAVE, zero barriers, DMA-staged x ----------------
extern "C" __global__ __launch_bounds__(256, 2)
void diffpool_main(const float* __restrict__ x,
                   const int* __restrict__ ei,
                   const float* __restrict__ bp,
                   const float* __restrict__ bl,
                   const float* __restrict__ ws,
                   float* __restrict__ out,
                   int E, int epg, int B)
{
    __shared__ __attribute__((aligned(16))) float sx[4][16][CI];            // 32768 B: x stage, 16-row chunks
    __shared__ __attribute__((aligned(16))) unsigned int sadjb[4][NN][AJW]; // 17408 B
    __shared__ __attribute__((aligned(16))) float sSm[4][NN][8];            // 8192 B
    // sSm row layout: [s0,s1,s2,s3 | s4, q, d, pad]

    const int t = threadIdx.x;
    const int lane = t & 63;
    const int wv = t >> 6;
    const int g = blockIdx.x * 4 + wv;    // one graph per wave
    if (g >= B) return;                   // safe: no barriers anywhere in this kernel

    unsigned int (*adj)[AJW] = sadjb[wv];
    float (*sm)[8] = sSm[wv];
    float* sxw = &sx[wv][0][0];           // [16][128] chunk buffer

    const int n = lane;
    const int ch = lane & 15;     // column chunk (16 lanes per row)
    const int rg = lane >> 4;     // row group 0..3

    // uniform scalars (SGPR)
    const float bp0 = bp[0], bp1 = bp[1], bp2 = bp[2], bp3 = bp[3], bp4 = bp[4];
    const float c_b1z = ws[WS_B1Z], c_b2w = ws[WS_B2W], c_bl = bl[0];

    // ---- edge loads first (oldest vmcnt entries -> atomics can start while stages fly) ----
    const int base = g * epg;
    int4 es0, es1, ed0, ed1;
    const bool fast = (epg == 512);
    if (fast) {
        es0 = *reinterpret_cast<const int4*>(ei + base + lane * 8);
        es1 = *reinterpret_cast<const int4*>(ei + base + lane * 8 + 4);
        ed0 = *reinterpret_cast<const int4*>(ei + E + base + lane * 8);
        ed1 = *reinterpret_cast<const int4*>(ei + E + base + lane * 8 + 4);
    }

    // ---- zero own adjacency row ----
    #pragma unroll
    for (int i = 0; i < AJW; ++i) adj[lane][i] = 0u;

    // ---- issue chunk-0 DMA stage (8 KB in flight, no VGPR payload) ----
    const char* xgb = (const char*)(x + (size_t)g * (NN * CI));
    #pragma unroll
    for (int k = 0; k < 8; ++k)
        gload_lds16(xgb + k * 1024 + (lane << 4), sxw + k * 256);

    // ---- adjacency atomics (compiler waits only the edge loads; stages stay in flight) ----
    if (fast) {
        EDGE(es0.x, ed0.x); EDGE(es0.y, ed0.y); EDGE(es0.z, ed0.z); EDGE(es0.w, ed0.w);
        EDGE(es1.x, ed1.x); EDGE(es1.y, ed1.y); EDGE(es1.z, ed1.z); EDGE(es1.w, ed1.w);
    } else {
        for (int j = lane; j < epg; j += 64) {
            const int sn = ei[base + j] & 63;
            const int dn = ei[E + base + j] & 63;
            atomicAdd(&adj[sn][dn >> 2], 1u << ((dn & 3) * 8));
        }
    }

    // ---- wc: per-lane Wc chunk (rows ch*8..+8, 6 cols = 48 floats, register-resident) ----
    float wc[48];
    {
        const float4* wc4 = reinterpret_cast<const float4*>(ws + WS_WC + ch * 48);
        #pragma unroll
        for (int i4 = 0; i4 < 12; ++i4)
            *reinterpret_cast<float4*>(&wc[i4 * 4]) = wc4[i4];
    }

    // ---- P1: 4 chunks of 16 rows; compute S0|q from LDS; single-buffer with fences ----
    #pragma unroll
    for (int c = 0; c < 4; ++c) {
        asm volatile("s_waitcnt vmcnt(0)" ::: "memory");   // chunk-c DMA (and wc) landed
        #pragma unroll
        for (int i = 0; i < 4; ++i) {
            const int rl = rg + 4 * i;            // local row in chunk
            const int row = c * 16 + rl;          // global row
            const float4 v0 = *reinterpret_cast<const float4*>(&sxw[rl * CI + ch * 8]);
            const float4 v1 = *reinterpret_cast<const float4*>(&sxw[rl * CI + ch * 8 + 4]);
            float acc[6];
            #pragma unroll
            for (int k = 0; k < 6; ++k)
                acc[k] = v0.x * wc[0*6+k] + v0.y * wc[1*6+k] + v0.z * wc[2*6+k] + v0.w * wc[3*6+k]
                       + v1.x * wc[4*6+k] + v1.y * wc[5*6+k] + v1.z * wc[6*6+k] + v1.w * wc[7*6+k];
            #pragma unroll
            for (int k = 0; k < 6; ++k) {
                float r = acc[k];
                r += __shfl_xor(r, 1, 16);
                r += __shfl_xor(r, 2, 16);
                r += __shfl_xor(r, 4, 16);
                r += __shfl_xor(r, 8, 16);
                acc[k] = r;
            }
            float val = acc[0];
            #pragma unroll
            for (int k = 1; k < 6; ++k) val = (ch == k) ? acc[k] : val;
            if (ch < 6)      sm[row][ch] = val;   // s0..s4 | q
            else if (ch < 8) sm[row][ch] = 0.f;   // init d/pad (d overwritten in S1)
        }
        asm volatile("s_waitcnt lgkmcnt(0)" ::: "memory"); // chunk-c LDS reads retired
        if (c < 3) {
            #pragma unroll
            for (int k = 0; k < 8; ++k)
                gload_lds16(xgb + (c + 1) * 8192 + k * 1024 + (lane << 4), sxw + k * 256);
        }
    }

    // ---- S1: adjacency row -> regs; degree from byte sums; d; s_pre + c (in regs) ----
    unsigned w[16];
    #pragma unroll
    for (int i = 0; i < 16; ++i) w[i] = adj[n][i];
    unsigned acc1 = 0u, acc2 = 0u;
    #pragma unroll
    for (int i = 0; i < 16; ++i) {
        acc1 += w[i] & 0x00FF00FFu;
        acc2 += (w[i] >> 8) & 0x00FF00FFu;
    }
    const unsigned rowsum = (acc1 & 0xFFFFu) + (acc1 >> 16) + (acc2 & 0xFFFFu) + (acc2 >> 16);
    const unsigned selfb = (adj[n][n >> 2] >> ((n & 3) * 8)) & 255u;
    const float dlane = rsqrtf((float)(rowsum + 1u - selfb));
    sm[n][6] = dlane;    // same-wave write; later broadcast reads program-ordered

    float a0 = 0.f, a1 = 0.f, a2 = 0.f, a3 = 0.f, a4 = 0.f, cp = 0.f;
    #pragma unroll
    for (int i = 0; i < 16; ++i) {
        #pragma unroll
        for (int b = 0; b < 4; ++b) {
            const int m = i * 4 + b;
            float al = (float)((w[i] >> (b * 8)) & 255u);
            al = (m == n) ? 1.f : al;
            const float4 s01 = *reinterpret_cast<const float4*>(&sm[m][0]); // broadcast
            const float4 s23 = *reinterpret_cast<const float4*>(&sm[m][4]); // {s4,q,d,pad}
            const float f = al * s23.z;             // al * d[m]
            a0 += f * s01.x; a1 += f * s01.y; a2 += f * s01.z; a3 += f * s01.w;
            a4 += f * s23.x;
            cp += f * s23.y;                        // c[n] += adj_l*d[m]*q[m]
        }
    }

    // ---- S2: softmax in registers; publish s to own row ----
    a0 = a0 * dlane + bp0; a1 = a1 * dlane + bp1; a2 = a2 * dlane + bp2;
    a3 = a3 * dlane + bp3; a4 = a4 * dlane + bp4;
    const float mx = fmaxf(fmaxf(fmaxf(a0, a1), fmaxf(a2, a3)), a4);
    a0 = expf(a0 - mx); a1 = expf(a1 - mx); a2 = expf(a2 - mx);
    a3 = expf(a3 - mx); a4 = expf(a4 - mx);
    const float inv = 1.f / (a0 + a1 + a2 + a3 + a4);
    float sv[5];
    sv[0] = a0 * inv; sv[1] = a1 * inv; sv[2] = a2 * inv; sv[3] = a3 * inv; sv[4] = a4 * inv;
    {
        float4 s01; s01.x = sv[0]; s01.y = sv[1]; s01.z = sv[2]; s01.w = sv[3];
        *reinterpret_cast<float4*>(&sm[n][0]) = s01;
        sm[n][4] = sv[4];
    }

    // ---- S3: U[n][:] = sum_m adj[n][m] * s[m][:] (raw adj), in registers ----
    float uv[5] = {0.f, 0.f, 0.f, 0.f, 0.f};
    #pragma unroll
    for (int i = 0; i < 16; ++i) {
        #pragma unroll
        for (int b = 0; b < 4; ++b) {
            const int m = i * 4 + b;
            const float c = (float)((w[i] >> (b * 8)) & 255u);
            const float4 s03 = *reinterpret_cast<const float4*>(&sm[m][0]); // broadcast
            const float s4r = sm[m][4];
            uv[0] += c * s03.x; uv[1] += c * s03.y; uv[2] += c * s03.z;
            uv[3] += c * s03.w; uv[4] += c * s4r;
        }
    }

    // ---- S4: adjp = s^T U via lane-outer-product + 25-value wave butterfly ----
    float pr[25];
    #pragma unroll
    for (int k = 0; k < 5; ++k)
        #pragma unroll
        for (int l = 0; l < 5; ++l)
            pr[k * 5 + l] = sv[k] * uv[l];
    #pragma unroll
    for (int p = 0; p < 25; ++p) {
        float r = pr[p];
        r += __shfl_xor(r, 1, 64);
        r += __shfl_xor(r, 2, 64);
        r += __shfl_xor(r, 4, 64);
        r += __shfl_xor(r, 8, 64);
        r += __shfl_xor(r, 16, 64);
        r += __shfl_xor(r, 32, 64);
        pr[p] = r;      // all lanes hold full adjp
    }

    // ---- S5: per-lane redundant scalar chain -> w[n], then final reduce ----
    float d2[5], cf[5];
    #pragma unroll
    for (int k = 0; k < 5; ++k) {
        float s_ = pr[k*5+0] + pr[k*5+1] + pr[k*5+2] + pr[k*5+3] + pr[k*5+4];
        s_ += 1.f - pr[k * 6];
        d2[k] = rsqrtf(fmaxf(s_, 1.f));
    }
    #pragma unroll
    for (int l = 0; l < 5; ++l) {
        float a = 0.f;
        #pragma unroll
        for (int k = 0; k < 5; ++k) a += d2[k] * pr[k * 5 + l];
        a += d2[l] * (1.f - pr[l * 6]);
        cf[l] = d2[l] * a;
    }
    const float t5 = cf[0]*sv[0] + cf[1]*sv[1] + cf[2]*sv[2] + cf[3]*sv[3] + cf[4]*sv[4];
    float v  = (dlane * t5) * cp;   // w[n] * c[n]
    float cb = t5;
    #pragma unroll
    for (int off = 32; off; off >>= 1) {
        v  += __shfl_down(v,  off, 64);
        cb += __shfl_down(cb, off, 64);
    }
    if (lane == 0)
        out[g] = v + cb * c_b1z + 5.f * c_b2w + c_bl;
}

extern "C" void kernel_launch(void* const* d_in, const int* in_sizes, int n_in,
                              void* d_out, int out_size, void* d_ws, size_t ws_size,
                              hipStream_t stream) {
    const float* x  = (const float*)d_in[0];
    const int*   ei = (const int*)d_in[1];
    // d_in[2] = batch (layout implied; unused)
    const float* Wp = (const float*)d_in[3];
    const float* bp = (const float*)d_in[4];
    const float* W1 = (const float*)d_in[5];
    const float* b1 = (const float*)d_in[6];
    const float* W2 = (const float*)d_in[7];
    const float* b2 = (const float*)d_in[8];
    const float* Wl = (const float*)d_in[9];
    const float* bl = (const float*)d_in[10];
    float* out = (float*)d_out;
    float* ws  = (float*)d_ws;

    const int B = out_size;            // 8192 graphs
    const int E = in_sizes[1] / 2;     // edge_index is [2, E]
    const int epg = E / B;             // 512 edges per graph

    zprep<<<1, 64, 0, stream>>>(W1, Wp, W2, Wl, b1, b2, ws);
    const int nb = (B + 3) / 4;        // 4 graphs (waves) per block
    diffpool_main<<<nb, 256, 0, stream>>>(x, ei, bp, bl, ws, out, E, epg, B);
}